// Round 1
// baseline (768.944 us; speedup 1.0000x reference)
//
#include <hip/hip_runtime.h>

typedef __attribute__((ext_vector_type(8))) short short8;     // 8 x bf16 (4 VGPRs)
typedef __attribute__((ext_vector_type(4))) float f32x4;      // MFMA accum
typedef __attribute__((ext_vector_type(4))) int int4v;        // 16B mover

typedef const __attribute__((address_space(1))) void* gas_t;
typedef __attribute__((address_space(3))) void* las_t;

__device__ __forceinline__ unsigned short f2bf(float f) {
  unsigned int u = __float_as_uint(f);
  u += 0x7fffu + ((u >> 16) & 1u);   // RNE
  return (unsigned short)(u >> 16);
}

// ---------------- fp32 -> bf16 convert (contiguous) ----------------
__global__ void cvt_bf16_kernel(const float* __restrict__ in,
                                unsigned short* __restrict__ out, int n) {
  int i = (blockIdx.x * 256 + threadIdx.x) * 4;
  if (i + 3 < n) {
    float4 v = *(const float4*)(in + i);
    ushort4 r;
    r.x = f2bf(v.x); r.y = f2bf(v.y); r.z = f2bf(v.z); r.w = f2bf(v.w);
    *(ushort4*)(out + i) = r;
  }
}

// ---------------- fp32 KxN -> bf16 NxK transpose ----------------
__global__ void transpose_cvt_kernel(const float* __restrict__ W,
                                     unsigned short* __restrict__ Wt,
                                     int K, int N) {
  __shared__ float t[32][33];
  int tx = threadIdx.x & 31, ty = threadIdx.x >> 5;   // 32 x 8
  int k0 = blockIdx.x * 32, n0 = blockIdx.y * 32;
  #pragma unroll
  for (int i = 0; i < 32; i += 8)
    t[ty + i][tx] = W[(size_t)(k0 + ty + i) * N + n0 + tx];
  __syncthreads();
  #pragma unroll
  for (int i = 0; i < 32; i += 8)
    Wt[(size_t)(n0 + ty + i) * K + k0 + tx] = f2bf(t[tx][ty + i]);
}

// ---------------- m97-style GEMM: C = A(MxK) * Bt(NxK)^T ----------------
// bf16 in, fp32 accum; F32OUT: fp32 C + bias, else bf16 C.
template<bool F32OUT>
__global__ __launch_bounds__(256, 2) void gemm_bt_kernel(
    const unsigned short* __restrict__ A,   // M x K bf16
    const unsigned short* __restrict__ Bt,  // N x K bf16
    void* __restrict__ Cptr, const float* __restrict__ bias,
    int M, int N, int K) {
  __shared__ __align__(16) unsigned short smem[2 * 128 * 64];
  unsigned short* As = smem;             // 128 x 64
  unsigned short* Bs = smem + 128 * 64;  // 128 x 64 (rows = n)

  const int tid  = threadIdx.x;
  const int wave = tid >> 6, lane = tid & 63;
  const int lrow = lane & 15, quad = lane >> 4;
  const int row0 = blockIdx.x * 128, col0 = blockIdx.y * 128;
  const int wm = (wave >> 1) * 64, wn = (wave & 1) * 64;
  const int srow = lane >> 3;          // row within 8-row group
  const int scol = (lane & 7) * 8;     // bf16 col (16B chunk)

  f32x4 zero = {0.f, 0.f, 0.f, 0.f};
  f32x4 acc[4][4];
  #pragma unroll
  for (int mi = 0; mi < 4; ++mi)
    #pragma unroll
    for (int ni = 0; ni < 4; ++ni) acc[mi][ni] = zero;

  for (int k0 = 0; k0 < K; k0 += 64) {
    #pragma unroll
    for (int i = 0; i < 4; ++i) {
      int r = (wave * 4 + i) * 8 + srow;            // 0..127; lds = base + lane*16
      int ga = row0 + r; if (ga > M - 1) ga = M - 1; // clamp M edge
      const unsigned short* gA = A + (size_t)ga * K + k0 + scol;
      __builtin_amdgcn_global_load_lds((gas_t)gA, (las_t)(As + r * 64 + scol), 16, 0, 0);
      const unsigned short* gB = Bt + (size_t)(col0 + r) * K + k0 + scol;
      __builtin_amdgcn_global_load_lds((gas_t)gB, (las_t)(Bs + r * 64 + scol), 16, 0, 0);
    }
    __syncthreads();
    #pragma unroll
    for (int kk = 0; kk < 64; kk += 32) {
      short8 av[4], bv[4];
      #pragma unroll
      for (int mi = 0; mi < 4; ++mi)
        av[mi] = *(const short8*)(As + (wm + mi * 16 + lrow) * 64 + kk + quad * 8);
      #pragma unroll
      for (int ni = 0; ni < 4; ++ni)
        bv[ni] = *(const short8*)(Bs + (wn + ni * 16 + lrow) * 64 + kk + quad * 8);
      #pragma unroll
      for (int mi = 0; mi < 4; ++mi)
        #pragma unroll
        for (int ni = 0; ni < 4; ++ni)
          acc[mi][ni] = __builtin_amdgcn_mfma_f32_16x16x32_bf16(av[mi], bv[ni], acc[mi][ni], 0, 0, 0);
    }
    __syncthreads();
  }

  if (F32OUT) {
    float* C = (float*)Cptr;
    #pragma unroll
    for (int mi = 0; mi < 4; ++mi)
      #pragma unroll
      for (int ni = 0; ni < 4; ++ni) {
        int col = col0 + wn + ni * 16 + lrow;
        float bv = bias[col];
        #pragma unroll
        for (int r = 0; r < 4; ++r) {
          int row = row0 + wm + mi * 16 + quad * 4 + r;
          if (row < M) C[(size_t)row * N + col] = acc[mi][ni][r] + bv;
        }
      }
  } else {
    // bf16 epilogue: wave-local LDS transpose -> 16B coalesced stores
    unsigned short* C = (unsigned short*)Cptr;
    unsigned short* Cw = smem + wave * 4096;  // 64x64 region per wave
    #pragma unroll
    for (int mi = 0; mi < 4; ++mi)
      #pragma unroll
      for (int ni = 0; ni < 4; ++ni)
        #pragma unroll
        for (int r = 0; r < 4; ++r)
          Cw[(mi * 16 + quad * 4 + r) * 64 + ni * 16 + lrow] = f2bf(acc[mi][ni][r]);
    #pragma unroll
    for (int it = 0; it < 8; ++it) {
      int row = it * 8 + (lane >> 3);
      int c8  = (lane & 7) * 8;
      int grow = row0 + wm + row;
      if (grow < M) {
        int4v v = *(const int4v*)(Cw + row * 64 + c8);
        *(int4v*)(C + (size_t)grow * N + col0 + wn + c8) = v;
      }
    }
  }
}

// ---------------- fused attention over 87 keys ----------------
// Qall: 65536 x 1280 ([tq | vq]); KVall: 1392 x 2560 ([Wk|Wv|Wvk|Wvv] proj)
// O: 65536 x 640. Grid: (qtile=64, h=8, b=16), 256 threads (4 waves x 16 rows).
__global__ __launch_bounds__(256, 2) void attn_kernel(
    const unsigned short* __restrict__ Q,
    const unsigned short* __restrict__ KV,
    unsigned short* __restrict__ O) {
  constexpr int DE = 160;   // [tq | vq] unified dim
  __shared__ __align__(16) unsigned short smem[96 * 160 + 64 * 160];
  unsigned short* Ke = smem;              // 96 x 160 (keys padded 87->96)
  unsigned short* Qe = smem + 96 * 160;   // 64 x 160
  unsigned short* P  = smem;              // 64 x 96 overlay (after scores)
  unsigned short* Vt = Qe;                // 80 x 96 overlay (after scores)

  const int tid = threadIdx.x;
  const int wave = tid >> 6, lane = tid & 63;
  const int lrow = lane & 15, quad = lane >> 4;
  const int qt = blockIdx.x, h = blockIdx.y, b = blockIdx.z;
  const size_t qbase = (size_t)(b * 4096 + qt * 64);

  // stage Qe = [tq | vq] : 64 rows x 20 chunks(8 bf16)
  for (int idx = tid; idx < 64 * 20; idx += 256) {
    int r = idx / 20, c = idx % 20;
    int gcol = (c < 10) ? (h * 80 + c * 8) : (640 + h * 80 + (c - 10) * 8);
    *(int4v*)(Qe + r * DE + c * 8) = *(const int4v*)(Q + (qbase + r) * 1280 + gcol);
  }
  // stage Ke: text keys -> [Ktext | 0], visual keys -> [0 | Kvis], pad rows = 0
  for (int idx = tid; idx < 96 * 20; idx += 256) {
    int r = idx / 20, c = idx % 20;
    int4v v = {0, 0, 0, 0};
    if (r < 87) {
      if (r < 77 && c < 10)
        v = *(const int4v*)(KV + (size_t)(b * 87 + r) * 2560 + h * 80 + c * 8);
      else if (r >= 77 && c >= 10)
        v = *(const int4v*)(KV + (size_t)(b * 87 + r) * 2560 + 1280 + h * 80 + (c - 10) * 8);
    }
    *(int4v*)(Ke + r * DE + c * 8) = v;
  }
  __syncthreads();

  // scores S = Qe * Ke^T : wave handles 16 q-rows x 96 key-cols
  f32x4 zero = {0.f, 0.f, 0.f, 0.f};
  f32x4 s[6];
  #pragma unroll
  for (int nt = 0; nt < 6; ++nt) s[nt] = zero;
  #pragma unroll
  for (int kc = 0; kc < 5; ++kc) {
    short8 a = *(const short8*)(Qe + (wave * 16 + lrow) * DE + kc * 32 + quad * 8);
    #pragma unroll
    for (int nt = 0; nt < 6; ++nt) {
      short8 bb = *(const short8*)(Ke + (nt * 16 + lrow) * DE + kc * 32 + quad * 8);
      s[nt] = __builtin_amdgcn_mfma_f32_16x16x32_bf16(a, bb, s[nt], 0, 0, 0);
    }
  }

  // softmax over 87 valid keys (cols); lane holds rows quad*4+r, col nt*16+lrow
  const float scale = 0.11180339887498949f;  // 1/sqrt(80)
  float mrow[4] = {-1e30f, -1e30f, -1e30f, -1e30f};
  #pragma unroll
  for (int nt = 0; nt < 6; ++nt) {
    bool valid = (nt * 16 + lrow) < 87;
    #pragma unroll
    for (int r = 0; r < 4; ++r) {
      float v = valid ? s[nt][r] * scale : -1e30f;
      s[nt][r] = v;
      mrow[r] = fmaxf(mrow[r], v);
    }
  }
  #pragma unroll
  for (int off = 1; off < 16; off <<= 1)
    #pragma unroll
    for (int r = 0; r < 4; ++r)
      mrow[r] = fmaxf(mrow[r], __shfl_xor(mrow[r], off, 64));
  float lsum[4] = {0.f, 0.f, 0.f, 0.f};
  #pragma unroll
  for (int nt = 0; nt < 6; ++nt)
    #pragma unroll
    for (int r = 0; r < 4; ++r) {
      float p = __expf(s[nt][r] - mrow[r]);
      s[nt][r] = p;
      lsum[r] += p;
    }
  #pragma unroll
  for (int off = 1; off < 16; off <<= 1)
    #pragma unroll
    for (int r = 0; r < 4; ++r)
      lsum[r] += __shfl_xor(lsum[r], off, 64);
  float inv[4];
  #pragma unroll
  for (int r = 0; r < 4; ++r) inv[r] = 1.0f / lsum[r];

  __syncthreads();  // everyone done reading Qe/Ke

  // write P (64 x 96, bf16) into Ke region
  #pragma unroll
  for (int nt = 0; nt < 6; ++nt)
    #pragma unroll
    for (int r = 0; r < 4; ++r)
      P[(wave * 16 + quad * 4 + r) * 96 + nt * 16 + lrow] = f2bf(s[nt][r] * inv[r]);

  // stage Vt (80 x 96) into Qe region: Vt[d][k] = V[k][d], pad k -> 0
  for (int idx = tid; idx < 80 * 96; idx += 256) {
    int d = idx / 96, kk = idx % 96;
    unsigned short v = 0;
    if (kk < 87) {
      int base = (kk < 77) ? 640 : 1920;
      v = KV[(size_t)(b * 87 + kk) * 2560 + base + h * 80 + d];
    }
    Vt[d * 96 + kk] = v;
  }
  __syncthreads();

  // O = P * V : 64 x 80, K = 96
  f32x4 o[5];
  #pragma unroll
  for (int nt = 0; nt < 5; ++nt) o[nt] = zero;
  #pragma unroll
  for (int kc = 0; kc < 3; ++kc) {
    short8 a = *(const short8*)(P + (wave * 16 + lrow) * 96 + kc * 32 + quad * 8);
    #pragma unroll
    for (int nt = 0; nt < 5; ++nt) {
      short8 bb = *(const short8*)(Vt + (nt * 16 + lrow) * 96 + kc * 32 + quad * 8);
      o[nt] = __builtin_amdgcn_mfma_f32_16x16x32_bf16(a, bb, o[nt], 0, 0, 0);
    }
  }
  #pragma unroll
  for (int nt = 0; nt < 5; ++nt)
    #pragma unroll
    for (int r = 0; r < 4; ++r) {
      size_t row = qbase + wave * 16 + quad * 4 + r;
      O[row * 640 + h * 80 + nt * 16 + lrow] = f2bf(o[nt][r]);
    }
}

// ---------------- host ----------------
extern "C" void kernel_launch(void* const* d_in, const int* in_sizes, int n_in,
                              void* d_out, int out_size, void* d_ws, size_t ws_size,
                              hipStream_t stream) {
  const float* x   = (const float*)d_in[0];
  const float* enc = (const float*)d_in[1];
  const float* Wq  = (const float*)d_in[2];
  const float* Wvq = (const float*)d_in[3];
  const float* Wk  = (const float*)d_in[4];
  const float* Wv  = (const float*)d_in[5];
  const float* Wvk = (const float*)d_in[6];
  const float* Wvv = (const float*)d_in[7];
  const float* Wo  = (const float*)d_in[8];
  const float* bo  = (const float*)d_in[9];
  float* out = (float*)d_out;
  char* ws = (char*)d_ws;

  // workspace layout (bytes)
  unsigned short* Qall  = (unsigned short*)(ws);                  // 65536x1280 bf16 = 167,772,160 B
  unsigned short* xbf   = (unsigned short*)(ws + 167772160ull);   // 65536x640  bf16 (later reused as O)
  unsigned short* encbf = (unsigned short*)(ws + 251658240ull);   // 1392x768
  unsigned short* KVall = (unsigned short*)(ws + 253796352ull);   // 1392x2560
  unsigned short* WqcT  = (unsigned short*)(ws + 260923392ull);   // 1280x640
  unsigned short* WkvT  = (unsigned short*)(ws + 262561792ull);   // 2560x768
  unsigned short* WoT   = (unsigned short*)(ws + 266493952ull);   // 640x640
  // total = 267,313,152 B

  cvt_bf16_kernel<<<40960, 256, 0, stream>>>(x, xbf, 41943040);
  cvt_bf16_kernel<<<1044, 256, 0, stream>>>(enc, encbf, 1069056);

  transpose_cvt_kernel<<<dim3(20, 20), 256, 0, stream>>>(Wq,  WqcT,             640, 640);
  transpose_cvt_kernel<<<dim3(20, 20), 256, 0, stream>>>(Wvq, WqcT + 640 * 640, 640, 640);
  transpose_cvt_kernel<<<dim3(24, 20), 256, 0, stream>>>(Wk,  WkvT,              768, 640);
  transpose_cvt_kernel<<<dim3(24, 20), 256, 0, stream>>>(Wv,  WkvT + 640 * 768,  768, 640);
  transpose_cvt_kernel<<<dim3(24, 20), 256, 0, stream>>>(Wvk, WkvT + 1280 * 768, 768, 640);
  transpose_cvt_kernel<<<dim3(24, 20), 256, 0, stream>>>(Wvv, WkvT + 1920 * 768, 768, 640);
  transpose_cvt_kernel<<<dim3(20, 20), 256, 0, stream>>>(Wo,  WoT,              640, 640);

  // KV projections: all 4 weights x all 87 rows (attention gathers valid slices)
  gemm_bt_kernel<false><<<dim3(11, 20), 256, 0, stream>>>(encbf, WkvT, KVall, nullptr, 1392, 2560, 768);
  // Q projections: [tq | vq]
  gemm_bt_kernel<false><<<dim3(512, 10), 256, 0, stream>>>(xbf, WqcT, Qall, nullptr, 65536, 1280, 640);
  // fused attention -> O (reuses xbf region)
  attn_kernel<<<dim3(64, 8, 16), 256, 0, stream>>>(Qall, KVall, xbf);
  // output projection + bias
  gemm_bt_kernel<true><<<dim3(512, 5), 256, 0, stream>>>(xbf, WoT, out, bo, 65536, 640, 640);
}

// Round 2
// 676.551 us; speedup vs baseline: 1.1366x; 1.1366x over previous
//
#include <hip/hip_runtime.h>

typedef __attribute__((ext_vector_type(8))) short short8;     // 8 x bf16 (4 VGPRs)
typedef __attribute__((ext_vector_type(4))) float f32x4;      // MFMA accum
typedef __attribute__((ext_vector_type(4))) int int4v;        // 16B mover

typedef const __attribute__((address_space(1))) void* gas_t;
typedef __attribute__((address_space(3))) void* las_t;

__device__ __forceinline__ unsigned short f2bf(float f) {
  unsigned int u = __float_as_uint(f);
  u += 0x7fffu + ((u >> 16) & 1u);   // RNE
  return (unsigned short)(u >> 16);
}

// ---------------- fp32 -> bf16 convert (contiguous) ----------------
__global__ void cvt_bf16_kernel(const float* __restrict__ in,
                                unsigned short* __restrict__ out, int n) {
  int i = (blockIdx.x * 256 + threadIdx.x) * 4;
  if (i + 3 < n) {
    float4 v = *(const float4*)(in + i);
    ushort4 r;
    r.x = f2bf(v.x); r.y = f2bf(v.y); r.z = f2bf(v.z); r.w = f2bf(v.w);
    *(ushort4*)(out + i) = r;
  }
}

// ---------------- fp32 KxN -> bf16 NxK transpose ----------------
__global__ void transpose_cvt_kernel(const float* __restrict__ W,
                                     unsigned short* __restrict__ Wt,
                                     int K, int N) {
  __shared__ float t[32][33];
  int tx = threadIdx.x & 31, ty = threadIdx.x >> 5;   // 32 x 8
  int k0 = blockIdx.x * 32, n0 = blockIdx.y * 32;
  #pragma unroll
  for (int i = 0; i < 32; i += 8)
    t[ty + i][tx] = W[(size_t)(k0 + ty + i) * N + n0 + tx];
  __syncthreads();
  #pragma unroll
  for (int i = 0; i < 32; i += 8)
    Wt[(size_t)(n0 + ty + i) * K + k0 + tx] = f2bf(t[tx][ty + i]);
}

// ---------------- V transpose: KVall -> VtG[b][h][d=80][k=96] ----------------
__global__ void vtrans_kernel(const unsigned short* __restrict__ KV,
                              unsigned short* __restrict__ VtG) {
  int idx = blockIdx.x * 256 + threadIdx.x;
  if (idx >= 16 * 8 * 80 * 96) return;
  int k = idx % 96;
  int d = (idx / 96) % 80;
  int h = (idx / (96 * 80)) % 8;
  int b = idx / (96 * 80 * 8);
  unsigned short v = 0;
  if (k < 87) {
    int base = (k < 77) ? 640 : 1920;  // tv at col 640, vv at col 1920
    v = KV[(size_t)(b * 87 + k) * 2560 + base + h * 80 + d];
  }
  VtG[idx] = v;
}

// ---------------- m97-style GEMM: C = A(MxK) * Bt(NxK)^T ----------------
template<bool F32OUT>
__global__ __launch_bounds__(256, 2) void gemm_bt_kernel(
    const unsigned short* __restrict__ A,   // M x K bf16
    const unsigned short* __restrict__ Bt,  // N x K bf16
    void* __restrict__ Cptr, const float* __restrict__ bias,
    int M, int N, int K) {
  __shared__ __align__(16) unsigned short smem[2 * 128 * 64];
  unsigned short* As = smem;             // 128 x 64
  unsigned short* Bs = smem + 128 * 64;  // 128 x 64 (rows = n)

  const int tid  = threadIdx.x;
  const int wave = tid >> 6, lane = tid & 63;
  const int lrow = lane & 15, quad = lane >> 4;
  const int row0 = blockIdx.x * 128, col0 = blockIdx.y * 128;
  const int wm = (wave >> 1) * 64, wn = (wave & 1) * 64;
  const int srow = lane >> 3;          // row within 8-row group
  const int scol = (lane & 7) * 8;     // bf16 col (16B chunk)

  f32x4 zero = {0.f, 0.f, 0.f, 0.f};
  f32x4 acc[4][4];
  #pragma unroll
  for (int mi = 0; mi < 4; ++mi)
    #pragma unroll
    for (int ni = 0; ni < 4; ++ni) acc[mi][ni] = zero;

  for (int k0 = 0; k0 < K; k0 += 64) {
    #pragma unroll
    for (int i = 0; i < 4; ++i) {
      int r = (wave * 4 + i) * 8 + srow;            // 0..127
      int ga = row0 + r; if (ga > M - 1) ga = M - 1; // clamp M edge
      const unsigned short* gA = A + (size_t)ga * K + k0 + scol;
      __builtin_amdgcn_global_load_lds((gas_t)gA, (las_t)(As + r * 64 + scol), 16, 0, 0);
      const unsigned short* gB = Bt + (size_t)(col0 + r) * K + k0 + scol;
      __builtin_amdgcn_global_load_lds((gas_t)gB, (las_t)(Bs + r * 64 + scol), 16, 0, 0);
    }
    __syncthreads();
    #pragma unroll
    for (int kk = 0; kk < 64; kk += 32) {
      short8 av[4], bv[4];
      #pragma unroll
      for (int mi = 0; mi < 4; ++mi)
        av[mi] = *(const short8*)(As + (wm + mi * 16 + lrow) * 64 + kk + quad * 8);
      #pragma unroll
      for (int ni = 0; ni < 4; ++ni)
        bv[ni] = *(const short8*)(Bs + (wn + ni * 16 + lrow) * 64 + kk + quad * 8);
      #pragma unroll
      for (int mi = 0; mi < 4; ++mi)
        #pragma unroll
        for (int ni = 0; ni < 4; ++ni)
          acc[mi][ni] = __builtin_amdgcn_mfma_f32_16x16x32_bf16(av[mi], bv[ni], acc[mi][ni], 0, 0, 0);
    }
    __syncthreads();
  }

  if (F32OUT) {
    float* C = (float*)Cptr;
    #pragma unroll
    for (int mi = 0; mi < 4; ++mi)
      #pragma unroll
      for (int ni = 0; ni < 4; ++ni) {
        int col = col0 + wn + ni * 16 + lrow;
        float bv = bias[col];
        #pragma unroll
        for (int r = 0; r < 4; ++r) {
          int row = row0 + wm + mi * 16 + quad * 4 + r;
          if (row < M) C[(size_t)row * N + col] = acc[mi][ni][r] + bv;
        }
      }
  } else {
    unsigned short* C = (unsigned short*)Cptr;
    unsigned short* Cw = smem + wave * 4096;  // 64x64 region per wave
    #pragma unroll
    for (int mi = 0; mi < 4; ++mi)
      #pragma unroll
      for (int ni = 0; ni < 4; ++ni)
        #pragma unroll
        for (int r = 0; r < 4; ++r)
          Cw[(mi * 16 + quad * 4 + r) * 64 + ni * 16 + lrow] = f2bf(acc[mi][ni][r]);
    #pragma unroll
    for (int it = 0; it < 8; ++it) {
      int row = it * 8 + (lane >> 3);
      int c8  = (lane & 7) * 8;
      int grow = row0 + wm + row;
      if (grow < M) {
        int4v v = *(const int4v*)(Cw + row * 64 + c8);
        *(int4v*)(C + (size_t)grow * N + col0 + wn + c8) = v;
      }
    }
  }
}

// ---------------- fused attention over 87 keys (v2) ----------------
// Q: 65536 x 1280 ([tq|vq]); KV: 1392 x 2560; VtG: [b][h][80][96]; O: 65536x640
// Grid: (qtile=64 rows, h=8, b=16), 256 threads = 4 waves x 16 q-rows.
// LDS: Ke 96x168 (32256 B) + Vt 80x104 (16640 B) = 48896 B -> 3 blocks/CU.
__global__ __launch_bounds__(256, 3) void attn_kernel(
    const unsigned short* __restrict__ Q,
    const unsigned short* __restrict__ KV,
    const unsigned short* __restrict__ VtG,
    unsigned short* __restrict__ O) {
  constexpr int KS = 168;   // Ke row stride (shorts): 84 dwords, 2-way banks (free)
  constexpr int PS = 104;   // P / Vt row stride: 52 dwords
  __shared__ __align__(16) unsigned short smem[96 * KS + 80 * PS];
  unsigned short* Ke = smem;              // 96 x KS
  unsigned short* Vt = smem + 96 * KS;    // 80 x PS
  unsigned short* P  = smem;              // 64 x PS overlay on Ke (after scores)

  const int tid = threadIdx.x;
  const int wave = tid >> 6, lane = tid & 63;
  const int lrow = lane & 15, quad = lane >> 4;
  const int qt = blockIdx.x, h = blockIdx.y, b = blockIdx.z;
  const size_t qbase = (size_t)(b * 4096 + qt * 64);

  // stage Vt (coalesced from VtG): 80 rows x 12 chunks
  const unsigned short* vg = VtG + (size_t)(b * 8 + h) * 80 * 96;
  for (int idx = tid; idx < 80 * 12; idx += 256) {
    int r = idx / 12, c = idx % 12;
    *(int4v*)(Vt + r * PS + c * 8) = *(const int4v*)(vg + r * 96 + c * 8);
  }
  // stage Ke: text keys -> [Ktext | 0], visual keys -> [0 | Kvis], pad rows = 0
  for (int idx = tid; idx < 96 * 20; idx += 256) {
    int r = idx / 20, c = idx % 20;
    int4v v = {0, 0, 0, 0};
    if (r < 87) {
      if (r < 77 && c < 10)
        v = *(const int4v*)(KV + (size_t)(b * 87 + r) * 2560 + h * 80 + c * 8);
      else if (r >= 77 && c >= 10)
        v = *(const int4v*)(KV + (size_t)(b * 87 + r) * 2560 + 1280 + h * 80 + (c - 10) * 8);
    }
    *(int4v*)(Ke + r * KS + c * 8) = v;
  }

  // Q A-fragments straight from global (16B/lane, each wave owns its 16 rows)
  const unsigned short* Qrow = Q + (qbase + wave * 16 + lrow) * 1280;
  short8 qfrag[5];
  #pragma unroll
  for (int kc = 0; kc < 5; ++kc) {
    int j = kc * 32 + quad * 8;                  // 0..152
    int gcol = h * 80 + j + (j >= 80 ? 560 : 0); // tq half vs vq half
    qfrag[kc] = *(const short8*)(Qrow + gcol);
  }
  __syncthreads();

  // scores S = Q * Ke^T : wave = 16 q-rows x 96 key-cols
  f32x4 zero = {0.f, 0.f, 0.f, 0.f};
  f32x4 s[6];
  #pragma unroll
  for (int nt = 0; nt < 6; ++nt) s[nt] = zero;
  #pragma unroll
  for (int kc = 0; kc < 5; ++kc) {
    #pragma unroll
    for (int nt = 0; nt < 6; ++nt) {
      short8 bb = *(const short8*)(Ke + (nt * 16 + lrow) * KS + kc * 32 + quad * 8);
      s[nt] = __builtin_amdgcn_mfma_f32_16x16x32_bf16(qfrag[kc], bb, s[nt], 0, 0, 0);
    }
  }

  // softmax over 87 valid key-cols; lane holds rows quad*4+r, col nt*16+lrow
  const float scale = 0.11180339887498949f;  // 1/sqrt(80)
  float mrow[4] = {-1e30f, -1e30f, -1e30f, -1e30f};
  #pragma unroll
  for (int nt = 0; nt < 6; ++nt) {
    bool valid = (nt * 16 + lrow) < 87;
    #pragma unroll
    for (int r = 0; r < 4; ++r) {
      float v = valid ? s[nt][r] * scale : -1e30f;
      s[nt][r] = v;
      mrow[r] = fmaxf(mrow[r], v);
    }
  }
  #pragma unroll
  for (int off = 1; off < 16; off <<= 1)
    #pragma unroll
    for (int r = 0; r < 4; ++r)
      mrow[r] = fmaxf(mrow[r], __shfl_xor(mrow[r], off, 64));
  float lsum[4] = {0.f, 0.f, 0.f, 0.f};
  #pragma unroll
  for (int nt = 0; nt < 6; ++nt)
    #pragma unroll
    for (int r = 0; r < 4; ++r) {
      float p = __expf(s[nt][r] - mrow[r]);
      s[nt][r] = p;
      lsum[r] += p;
    }
  #pragma unroll
  for (int off = 1; off < 16; off <<= 1)
    #pragma unroll
    for (int r = 0; r < 4; ++r)
      lsum[r] += __shfl_xor(lsum[r], off, 64);
  float inv[4];
  #pragma unroll
  for (int r = 0; r < 4; ++r) inv[r] = 1.0f / lsum[r];

  __syncthreads();  // all waves done reading Ke before P overlays it

  // write P (64 x 96 bf16, stride PS) into Ke region — each wave its own rows
  #pragma unroll
  for (int nt = 0; nt < 6; ++nt)
    #pragma unroll
    for (int r = 0; r < 4; ++r)
      P[(wave * 16 + quad * 4 + r) * PS + nt * 16 + lrow] = f2bf(s[nt][r] * inv[r]);

  // O = P * V : 64 x 80, K = 96 (wave reads only its own P rows -> no barrier)
  f32x4 o[5];
  #pragma unroll
  for (int nt = 0; nt < 5; ++nt) o[nt] = zero;
  #pragma unroll
  for (int kc = 0; kc < 3; ++kc) {
    short8 a = *(const short8*)(P + (wave * 16 + lrow) * PS + kc * 32 + quad * 8);
    #pragma unroll
    for (int nt = 0; nt < 5; ++nt) {
      short8 bb = *(const short8*)(Vt + (nt * 16 + lrow) * PS + kc * 32 + quad * 8);
      o[nt] = __builtin_amdgcn_mfma_f32_16x16x32_bf16(a, bb, o[nt], 0, 0, 0);
    }
  }

  // wave-local transpose through own P rows -> coalesced 16B stores
  unsigned short* Ow = P + wave * 16 * PS;
  #pragma unroll
  for (int nt = 0; nt < 5; ++nt)
    #pragma unroll
    for (int r = 0; r < 4; ++r)
      Ow[(quad * 4 + r) * PS + nt * 16 + lrow] = f2bf(o[nt][r]);
  for (int idx = lane; idx < 160; idx += 64) {
    int r = idx / 10, c = idx % 10;
    *(int4v*)(O + (qbase + wave * 16 + r) * 640 + h * 80 + c * 8) =
        *(const int4v*)(Ow + r * PS + c * 8);
  }
}

// ---------------- host ----------------
extern "C" void kernel_launch(void* const* d_in, const int* in_sizes, int n_in,
                              void* d_out, int out_size, void* d_ws, size_t ws_size,
                              hipStream_t stream) {
  const float* x   = (const float*)d_in[0];
  const float* enc = (const float*)d_in[1];
  const float* Wq  = (const float*)d_in[2];
  const float* Wvq = (const float*)d_in[3];
  const float* Wk  = (const float*)d_in[4];
  const float* Wv  = (const float*)d_in[5];
  const float* Wvk = (const float*)d_in[6];
  const float* Wvv = (const float*)d_in[7];
  const float* Wo  = (const float*)d_in[8];
  const float* bo  = (const float*)d_in[9];
  float* out = (float*)d_out;
  char* ws = (char*)d_ws;

  // workspace layout (bytes)
  unsigned short* Qall  = (unsigned short*)(ws);                  // 65536x1280 bf16
  unsigned short* xbf   = (unsigned short*)(ws + 167772160ull);   // 65536x640 (reused as O)
  unsigned short* encbf = (unsigned short*)(ws + 251658240ull);   // 1392x768
  unsigned short* KVall = (unsigned short*)(ws + 253796352ull);   // 1392x2560
  unsigned short* WqcT  = (unsigned short*)(ws + 260923392ull);   // 1280x640
  unsigned short* WkvT  = (unsigned short*)(ws + 262561792ull);   // 2560x768 (dead after KV gemm)
  unsigned short* WoT   = (unsigned short*)(ws + 266493952ull);   // 640x640
  unsigned short* VtG   = WkvT;  // 16*8*80*96 bf16 = 1.97 MB, overlays dead WkvT

  cvt_bf16_kernel<<<40960, 256, 0, stream>>>(x, xbf, 41943040);
  cvt_bf16_kernel<<<1044, 256, 0, stream>>>(enc, encbf, 1069056);

  transpose_cvt_kernel<<<dim3(20, 20), 256, 0, stream>>>(Wq,  WqcT,             640, 640);
  transpose_cvt_kernel<<<dim3(20, 20), 256, 0, stream>>>(Wvq, WqcT + 640 * 640, 640, 640);
  transpose_cvt_kernel<<<dim3(24, 20), 256, 0, stream>>>(Wk,  WkvT,              768, 640);
  transpose_cvt_kernel<<<dim3(24, 20), 256, 0, stream>>>(Wv,  WkvT + 640 * 768,  768, 640);
  transpose_cvt_kernel<<<dim3(24, 20), 256, 0, stream>>>(Wvk, WkvT + 1280 * 768, 768, 640);
  transpose_cvt_kernel<<<dim3(24, 20), 256, 0, stream>>>(Wvv, WkvT + 1920 * 768, 768, 640);
  transpose_cvt_kernel<<<dim3(20, 20), 256, 0, stream>>>(Wo,  WoT,              640, 640);

  // KV projections (all 4 weights x all 87 enc rows)
  gemm_bt_kernel<false><<<dim3(11, 20), 256, 0, stream>>>(encbf, WkvT, KVall, nullptr, 1392, 2560, 768);
  // V transpose for attention (overwrites WkvT region — KV gemm already done)
  vtrans_kernel<<<3840, 256, 0, stream>>>(KVall, VtG);
  // Q projections: [tq | vq]
  gemm_bt_kernel<false><<<dim3(512, 10), 256, 0, stream>>>(xbf, WqcT, Qall, nullptr, 65536, 1280, 640);
  // fused attention -> O (reuses xbf region)
  attn_kernel<<<dim3(64, 8, 16), 256, 0, stream>>>(Qall, KVall, VtG, xbf);
  // output projection + bias
  gemm_bt_kernel<true><<<dim3(512, 5), 256, 0, stream>>>(xbf, WoT, out, bo, 65536, 640, 640);
}